// Round 5
// baseline (355.417 us; speedup 1.0000x reference)
//
#include <hip/hip_runtime.h>

// ---------------------------------------------------------------------------
// FCGF_point_att2_ican_fc: per-point score -> global BN(1) -> per-segment
// softmax attention pooling -> FC(32,64) -> BN(64).
//
// R5: 2 dispatches, no cooperative launch (R4: hipLaunchCooperativeKernel
// never executed under the harness's graph capture -> output stayed zero).
//   A (k_stats): z-stat double partials; block 0 zeros gnum/gden/counter.
//   B (k_pool):  every block redundantly reduces the 1024 partials -> c1,c2
//                (deterministic, ~1-2 us, L2-hot), pool loop, atomics;
//                decoupled last-block-done epilogue (FC + BN -> out) using a
//                device-scope atomic counter (no spin, no co-residency req).
// All register arrays statically indexed (R3 lesson: dynamic idx => scratch
// spill, 105 MB WRITE_SIZE). __launch_bounds__(256,4) keeps VGPR<=128.
// ---------------------------------------------------------------------------

#define EPS 1e-5f
#define NSB 1024          // kernel A blocks (also # of double-pair partials)
#define CHUNKS 16         // kernel B: blocks per segment

// workspace layout (bytes)
#define WS_DPART   0          // double[2*NSB] = 16384 B
#define WS_GNUM    16384      // float[64*32]
#define WS_GDEN    24576      // float[64]
#define WS_CNT     24832      // unsigned int

// ---------------------------------------------------------------------------
// Kernel A: grid-stride z-stats; per-block double partials (sum z, sum z^2).
// Block 0 additionally zeros the accumulators/counter for kernel B (kernel
// boundary makes these visible device-wide).
__global__ __launch_bounds__(256, 4) void k_stats(const float* __restrict__ x,
                                                  const float* __restrict__ w1,
                                                  const float* __restrict__ b1,
                                                  int N, int B,
                                                  double* __restrict__ dpart,
                                                  float* __restrict__ gnum,
                                                  float* __restrict__ gden,
                                                  unsigned int* __restrict__ cnt) {
    const int tid = threadIdx.x;
    if (blockIdx.x == 0) {
        for (int i = tid; i < B * 32; i += 256) gnum[i] = 0.f;
        if (tid < B) gden[tid] = 0.f;
        if (tid == 0) *cnt = 0u;
    }

    const float b1v = b1[0];
    const float4* __restrict__ xv = (const float4*)x;
    const int stride = gridDim.x * 256;

    double accZ = 0.0, accZZ = 0.0;
    for (int row = blockIdx.x * 256 + tid; row < N; row += stride) {
        const float4* __restrict__ rp = xv + (size_t)row * 8;
        float4 v[8];
#pragma unroll
        for (int i = 0; i < 8; ++i) v[i] = rp[i];
        float z = b1v;
#pragma unroll
        for (int i = 0; i < 8; ++i) {
            z = fmaf(v[i].x, w1[4 * i + 0], z);
            z = fmaf(v[i].y, w1[4 * i + 1], z);
            z = fmaf(v[i].z, w1[4 * i + 2], z);
            z = fmaf(v[i].w, w1[4 * i + 3], z);
        }
        accZ  += (double)z;
        accZZ += (double)z * (double)z;
    }

    __shared__ double sZ[256], sZZ[256];
    sZ[tid] = accZ; sZZ[tid] = accZZ;
    __syncthreads();
    for (int s = 128; s > 0; s >>= 1) {
        if (tid < s) { sZ[tid] += sZ[tid + s]; sZZ[tid] += sZZ[tid + s]; }
        __syncthreads();
    }
    if (tid == 0) {
        dpart[2 * blockIdx.x]     = sZ[0];
        dpart[2 * blockIdx.x + 1] = sZZ[0];
    }
}

// ---------------------------------------------------------------------------
// Kernel B: per-block redundant consts reduction -> pool -> atomics ->
// last-block-done epilogue.
__global__ __launch_bounds__(256, 4) void k_pool(const float* __restrict__ x,
                                                 const int* __restrict__ length,
                                                 const float* __restrict__ w1,
                                                 const float* __restrict__ b1,
                                                 const float* __restrict__ g1,
                                                 const float* __restrict__ beta1,
                                                 const float* __restrict__ W2,
                                                 const float* __restrict__ b2,
                                                 const float* __restrict__ g2,
                                                 const float* __restrict__ beta2,
                                                 float* __restrict__ out,
                                                 int N, int B,
                                                 const double* __restrict__ dpart,
                                                 float* __restrict__ gnum,
                                                 float* __restrict__ gden,
                                                 unsigned int* __restrict__ cnt) {
    const int tid = threadIdx.x;
    const int c = blockIdx.x, b = blockIdx.y;
    const int nblk = gridDim.x * gridDim.y;

    __shared__ double sZ[256], sZZ[256];
    __shared__ float sc[2];
    __shared__ float sred[4][33];
    __shared__ int sseg[2];

    // segment extent (B=64: trivial scalar scan on thread 0)
    if (tid == 0) {
        int o = 0;
        for (int i = 0; i < b; ++i) o += length[i];
        sseg[0] = o; sseg[1] = length[b];
    }

    // --- redundant consts reduction: 2*NSB doubles, 4 pairs/thread ---------
    {
        double aZ = 0.0, aZZ = 0.0;
#pragma unroll
        for (int k = 0; k < NSB / 256; ++k) {
            int i = k * 256 + tid;
            aZ  += dpart[2 * i];
            aZZ += dpart[2 * i + 1];
        }
        sZ[tid] = aZ; sZZ[tid] = aZZ;
        __syncthreads();
        for (int s = 128; s > 0; s >>= 1) {
            if (tid < s) { sZ[tid] += sZ[tid + s]; sZZ[tid] += sZZ[tid + s]; }
            __syncthreads();
        }
        if (tid == 0) {
            double mu  = sZ[0] / (double)N;
            double var = sZZ[0] / (double)N - mu * mu;
            float c1 = (float)((double)g1[0] / sqrt(var + (double)EPS));
            sc[0] = c1;
            sc[1] = beta1[0] - (float)(c1 * mu);
        }
        __syncthreads();
    }
    const float c1 = sc[0], c2 = sc[1];
    const int off = sseg[0], len = sseg[1];
    const int rpc = (len + CHUNKS - 1) / CHUNKS;
    const int r0 = c * rpc, r1 = min(r0 + rpc, len);

    const float b1v = b1[0];
    const float4* __restrict__ xv = (const float4*)x;

    // --- pool loop ----------------------------------------------------------
    float4 acc[8];
#pragma unroll
    for (int i = 0; i < 8; ++i) acc[i] = make_float4(0.f, 0.f, 0.f, 0.f);
    float accE = 0.f;

    for (int r = r0 + tid; r < r1; r += 256) {
        const float4* __restrict__ rp = xv + (size_t)(off + r) * 8;
        float4 v[8];
#pragma unroll
        for (int i = 0; i < 8; ++i) v[i] = rp[i];
        float z = b1v, m = 0.f;
#pragma unroll
        for (int i = 0; i < 8; ++i) {
            z = fmaf(v[i].x, w1[4 * i + 0], z);
            z = fmaf(v[i].y, w1[4 * i + 1], z);
            z = fmaf(v[i].z, w1[4 * i + 2], z);
            z = fmaf(v[i].w, w1[4 * i + 3], z);
            m += v[i].x + v[i].y + v[i].z + v[i].w;
        }
        float s = (c1 * z + c2) * m * 0.03125f;
        float e = __expf(s);
#pragma unroll
        for (int i = 0; i < 8; ++i) {
            acc[i].x = fmaf(e, v[i].x, acc[i].x);
            acc[i].y = fmaf(e, v[i].y, acc[i].y);
            acc[i].z = fmaf(e, v[i].z, acc[i].z);
            acc[i].w = fmaf(e, v[i].w, acc[i].w);
        }
        accE += e;
    }

    // --- wave butterfly (static indices), cross-wave via LDS, 33 atomics ----
#pragma unroll
    for (int msk = 1; msk < 64; msk <<= 1) {
#pragma unroll
        for (int i = 0; i < 8; ++i) {
            acc[i].x += __shfl_xor(acc[i].x, msk);
            acc[i].y += __shfl_xor(acc[i].y, msk);
            acc[i].z += __shfl_xor(acc[i].z, msk);
            acc[i].w += __shfl_xor(acc[i].w, msk);
        }
        accE += __shfl_xor(accE, msk);
    }
    const int wave = tid >> 6;
    const int lane = tid & 63;
    if (lane == 0) {
#pragma unroll
        for (int i = 0; i < 8; ++i) {
            sred[wave][4 * i + 0] = acc[i].x;
            sred[wave][4 * i + 1] = acc[i].y;
            sred[wave][4 * i + 2] = acc[i].z;
            sred[wave][4 * i + 3] = acc[i].w;
        }
        sred[wave][32] = accE;
    }
    __syncthreads();
    if (tid < 33) {
        float s = sred[0][tid] + sred[1][tid] + sred[2][tid] + sred[3][tid];
        if (tid < 32) atomicAdd(&gnum[b * 32 + tid], s);
        else          atomicAdd(&gden[b], s);
    }

    // --- decoupled last-block-done epilogue ---------------------------------
    __threadfence();
    __shared__ unsigned int sold;
    __syncthreads();
    if (tid == 0) sold = atomicAdd(cnt, 1u);
    __syncthreads();
    if (sold != (unsigned int)(nblk - 1)) return;
    __threadfence();

    __shared__ float pooled[64 * 32];
    __shared__ float hmat[64 * 64];
    __shared__ float mu2[64], isd[64];

    for (int i = tid; i < B * 32; i += 256) {
        int bb = i >> 5;
        float num = atomicAdd(&gnum[i], 0.f);     // device-scope read
        float den = atomicAdd(&gden[bb], 0.f);
        pooled[i] = num / (den * (float)length[bb]);
    }
    __syncthreads();

    const int j = tid & 63;
    const int g = tid >> 6;
    for (int r = 0; r < 16; ++r) {
        int bb = g * 16 + r;
        if (bb < B) {
            float hv = b2[j];
            for (int k = 0; k < 32; ++k)
                hv += pooled[bb * 32 + k] * W2[k * 64 + j];
            hmat[bb * 64 + j] = hv;
        }
    }
    __syncthreads();

    if (tid < 64) {
        float m = 0.f;
        for (int bb = 0; bb < B; ++bb) m += hmat[bb * 64 + tid];
        m /= (float)B;
        float v = 0.f;
        for (int bb = 0; bb < B; ++bb) { float d = hmat[bb * 64 + tid] - m; v += d * d; }
        v /= (float)B;
        mu2[tid] = m;
        isd[tid] = rsqrtf(v + EPS);
    }
    __syncthreads();

    for (int r = 0; r < 16; ++r) {
        int bb = g * 16 + r;
        if (bb < B) {
            int idx = bb * 64 + j;
            out[idx] = g2[j] * (hmat[idx] - mu2[j]) * isd[j] + beta2[j];
        }
    }
}

// ---------------------------------------------------------------------------
extern "C" void kernel_launch(void* const* d_in, const int* in_sizes, int n_in,
                              void* d_out, int out_size, void* d_ws, size_t ws_size,
                              hipStream_t stream) {
    const float* x      = (const float*)d_in[0];
    const int*   length = (const int*)  d_in[1];
    const float* w1     = (const float*)d_in[2];
    const float* b1     = (const float*)d_in[3];
    const float* g1     = (const float*)d_in[4];
    const float* beta1  = (const float*)d_in[5];
    const float* W2     = (const float*)d_in[6];
    const float* b2     = (const float*)d_in[7];
    const float* g2     = (const float*)d_in[8];
    const float* beta2  = (const float*)d_in[9];
    float* out = (float*)d_out;

    const int N = in_sizes[0] / 32;
    const int B = in_sizes[1];

    char* ws = (char*)d_ws;
    double*       dpart = (double*)      (ws + WS_DPART);
    float*        gnum  = (float*)       (ws + WS_GNUM);
    float*        gden  = (float*)       (ws + WS_GDEN);
    unsigned int* cnt   = (unsigned int*)(ws + WS_CNT);

    k_stats<<<NSB, 256, 0, stream>>>(x, w1, b1, N, B, dpart, gnum, gden, cnt);
    k_pool <<<dim3(CHUNKS, B), 256, 0, stream>>>(x, length, w1, b1, g1, beta1,
                                                 W2, b2, g2, beta2, out, N, B,
                                                 dpart, gnum, gden, cnt);
}